// Round 1
// baseline (7067.171 us; speedup 1.0000x reference)
//
#include <hip/hip_runtime.h>
#include <cstdint>
#include <cstddef>

// ============================================================================
// LSTMCellQ bit-exact reproduction.
// Key requirements discovered in analysis:
//  - jax.random noise must be reproduced BIT-EXACTLY (thresholded MVM).
//  - einsum must be k-ascending single-accumulator f32 with fused MAC.
//  - jnp.round == rintf (round-half-even). No FP contraction on replicated ops.
// RNG bets this round: threefry_partitionable=True (foldlike split,
// bits = x0 ^ x1 of block (0, j)); XLA/CHLO Giles erfinv-f32; device logf.
// ============================================================================

struct KPc { uint32_t a, b; };

__host__ __device__ constexpr KPc ctf(uint32_t k0, uint32_t k1v, uint32_t c0, uint32_t c1) {
  uint32_t ks2 = k0 ^ k1v ^ 0x1BD11BDAu;
  uint32_t x0 = c0 + k0;
  uint32_t x1 = c1 + k1v;
  uint32_t r0[4] = {13u, 15u, 26u, 6u};
  uint32_t r1[4] = {17u, 29u, 16u, 24u};
  uint32_t ks[3] = {k0, k1v, ks2};
  for (int g = 0; g < 5; ++g) {
    for (int j = 0; j < 4; ++j) {
      uint32_t rr = (g & 1) ? r1[j] : r0[j];
      x0 += x1;
      x1 = (x1 << rr) | (x1 >> (32u - rr));
      x1 ^= x0;
    }
    ks2 = ks[(g + 1) % 3];           // reuse var name as temp is fine
    x0 += ks[(g + 1) % 3];
    x1 += ks[(g + 2) % 3] + (uint32_t)(g + 1);
  }
  return KPc{x0, x1};
}

// key(42) -> data (0,42). Foldlike split: key_i = block(key, (0, i)).
constexpr KPc K1K  = ctf(0u, 42u, 0u, 0u);   // k1
constexpr KPc K2K  = ctf(0u, 42u, 0u, 1u);   // k2
constexpr KPc KWIH = ctf(K1K.a, K1K.b, 0u, 0u); // kw for ih
constexpr KPc KBIH = ctf(K1K.a, K1K.b, 0u, 1u); // kb for ih
constexpr KPc KWHH = ctf(K2K.a, K2K.b, 0u, 0u);
constexpr KPc KBHH = ctf(K2K.a, K2K.b, 0u, 1u);

__device__ __forceinline__ uint32_t tf_bits(uint32_t k0, uint32_t k1v, uint32_t j) {
  // partitionable 32-bit random_bits: counts64 = j -> (hi=0, lo=j); bits = x0 ^ x1
  KPc r = ctf(k0, k1v, 0u, j);
  return r.a ^ r.b;
}

// ---------------- float max-reduction with order-encoded uint ----------------
__device__ __forceinline__ unsigned encf(float f) {
  unsigned u = __float_as_uint(f);
  return (u & 0x80000000u) ? ~u : (u | 0x80000000u);
}
__device__ __forceinline__ float decf(unsigned e) {
  unsigned u = (e & 0x80000000u) ? (e & 0x7FFFFFFFu) : ~e;
  return __uint_as_float(u);
}

__global__ void rmax_kernel(const float* __restrict__ x, int n, unsigned* __restrict__ out) {
  unsigned best = 0u;
  for (int i = blockIdx.x * blockDim.x + threadIdx.x; i < n; i += gridDim.x * blockDim.x) {
    unsigned e = encf(x[i]);
    best = best > e ? best : e;
  }
  for (int off = 32; off > 0; off >>= 1) {
    unsigned o = __shfl_down(best, off, 64);
    best = best > o ? best : o;
  }
  __shared__ unsigned sm[4];
  int lane = threadIdx.x & 63, wv = threadIdx.x >> 6;
  if (lane == 0) sm[wv] = best;
  __syncthreads();
  if (threadIdx.x == 0) {
    unsigned b = sm[0];
    for (int i = 1; i < 4; ++i) b = b > sm[i] ? b : sm[i];
    atomicMax(out, b);
  }
}

// ---------------- XLA-replicated erfinv / uniform->normal ----------------
__device__ __forceinline__ float xla_log1p(float t) {
  // XLA EmitLog1p: |t| < 1e-4 ? (1 + (-0.5)*t)*t : log(t + 1)
  float small = __fmul_rn(__fadd_rn(__fmul_rn(-0.5f, t), 1.0f), t);
  float large = logf(__fadd_rn(t, 1.0f));
  return (fabsf(t) < 1e-4f) ? small : large;
}

__device__ __forceinline__ float xla_erfinv(float x) {
  float w = -xla_log1p(-__fmul_rn(x, x));
  float p;
  if (w < 5.0f) {
    float ww = __fadd_rn(w, -2.5f);
    p = 2.81022636e-08f;
    p = __fadd_rn(3.43273939e-07f, __fmul_rn(p, ww));
    p = __fadd_rn(-3.5233877e-06f, __fmul_rn(p, ww));
    p = __fadd_rn(-4.39150654e-06f, __fmul_rn(p, ww));
    p = __fadd_rn(0.00021858087f, __fmul_rn(p, ww));
    p = __fadd_rn(-0.00125372503f, __fmul_rn(p, ww));
    p = __fadd_rn(-0.00417768164f, __fmul_rn(p, ww));
    p = __fadd_rn(0.246640727f, __fmul_rn(p, ww));
    p = __fadd_rn(1.50140941f, __fmul_rn(p, ww));
  } else {
    float ww = __fadd_rn(sqrtf(w), -3.0f);
    p = -0.000200214257f;
    p = __fadd_rn(0.000100950558f, __fmul_rn(p, ww));
    p = __fadd_rn(0.00134934322f, __fmul_rn(p, ww));
    p = __fadd_rn(-0.00367342844f, __fmul_rn(p, ww));
    p = __fadd_rn(0.00573950773f, __fmul_rn(p, ww));
    p = __fadd_rn(-0.0076224613f, __fmul_rn(p, ww));
    p = __fadd_rn(0.00943887047f, __fmul_rn(p, ww));
    p = __fadd_rn(1.00167406f, __fmul_rn(p, ww));
    p = __fadd_rn(2.83297682f, __fmul_rn(p, ww));
  }
  return __fmul_rn(p, x);
}

__device__ __forceinline__ float normal_from_bits(uint32_t bits) {
  // jax _uniform: bitcast((bits>>9)|0x3f800000) - 1; * (hi-lo==2.0f) + lo; max(lo, .)
  float u01 = __uint_as_float((bits >> 9) | 0x3f800000u) - 1.0f;    // exact
  const float lo = -0x1.fffffep-1f;                                 // nextafter(-1,0)
  float u = fmaxf(lo, __fadd_rn(__fmul_rn(u01, 2.0f), lo));
  return __fmul_rn(0x1.6a09e6p+0f /* f32(sqrt(2)) */, xla_erfinv(u));
}

// quant(x, 8, 1.0) -- exact on 1/128 grid
__device__ __forceinline__ float quantw(float x) {
  float xs = fminf(fmaxf(x, -0.9921875f), 0.9921875f);
  return __fmul_rn(rintf(__fmul_rn(xs, 128.0f)), 0.0078125f);
}

// ---------------- noisy term materialization ----------------
__global__ void gen_terms_kernel(const float* __restrict__ W, float* __restrict__ T, int n,
                                 const unsigned* __restrict__ encp, uint32_t k0, uint32_t k1v) {
  int j = blockIdx.x * 256 + threadIdx.x;
  if (j >= n) return;
  float wmax = decf(*encp);
  float nrm = normal_from_bits(tf_bits(k0, k1v, (uint32_t)j));
  float nw = __fmul_rn(__fmul_rn(nrm, wmax), 0.1f);
  T[j] = __fadd_rn(quantw(W[j]), nw);
}

__global__ void gen_bias_kernel(const float* __restrict__ bsrc, float* __restrict__ bq,
                                float* __restrict__ nb, int n,
                                const unsigned* __restrict__ encp, uint32_t k0, uint32_t k1v) {
  int j = blockIdx.x * 256 + threadIdx.x;
  if (j >= n) return;
  float bmax = decf(*encp);
  float nrm = normal_from_bits(tf_bits(k0, k1v, (uint32_t)j));
  bq[j] = quantw(bsrc[j]);
  nb[j] = __fmul_rn(__fmul_rn(nrm, bmax), 0.1f);
}

// ---------------- bitplane nibble precompute (transposed [i][b]) ----------------
__global__ void kv_kernel(const float* __restrict__ x, const float* __restrict__ ap,
                          const float* __restrict__ offp, unsigned char* __restrict__ kvT,
                          int Kdim) {
  int j = blockIdx.x * 256 + threadIdx.x;
  int n = 4096 * Kdim;
  if (j >= n) return;
  int b = j / Kdim, i = j - b * Kdim;
  float a = ap[0], off = offp[0];
  float v = fmaxf(-a, fminf(x[j], a));                       // pact = clip
  float t = __fdiv_rn(__fadd_rn(v, off), __fmul_rn(a, 2.0f));
  int k = (int)rintf(__fmul_rn(15.0f, t));                   // l1 = 2^4 - 1
  kvT[(size_t)i * 4096 + b] = (unsigned char)(k & 15);
}

// ---------------- binary GEMM: exact sequential-k f32 accumulation ----------------
// Each thread: 1 column c, 32 batch rows, 4 bitplanes => 128 f32 accumulators.
// fmaf(bit, T, acc) is rounding-identical to the reference's sequential MAC chain.
__global__ __launch_bounds__(256, 2) void gemm_bits_kernel(
    const float* __restrict__ T, const float* __restrict__ bq, const float* __restrict__ nb,
    const unsigned char* __restrict__ kvT, unsigned char* __restrict__ Kp,
    int K, int isHH) {
  const int c = blockIdx.x * 256 + threadIdx.x;
  const int b0 = blockIdx.y * 32;
  float acc[32][4];
#pragma unroll
  for (int r = 0; r < 32; ++r) {
    acc[r][0] = 0.0f; acc[r][1] = 0.0f; acc[r][2] = 0.0f; acc[r][3] = 0.0f;
  }
  const size_t mstride = (size_t)K * 4096;
  for (int k = 0; k < K; ++k) {
    const float* tp = T + (size_t)k * 4096 + c;
    float t0 = tp[0];
    float t1 = tp[mstride];
    float t2 = tp[2 * mstride];
    float t3 = tp[3 * mstride];
    const uint32_t* kw = (const uint32_t*)(kvT + (size_t)k * 4096 + b0);
#pragma unroll
    for (int w8 = 0; w8 < 8; ++w8) {
      uint32_t wv = kw[w8];
#pragma unroll
      for (int bb = 0; bb < 4; ++bb) {
        const int r = w8 * 4 + bb;
        uint32_t kb = (wv >> (bb * 8)) & 0xFu;
        float f0 = (kb & 8u) ? 1.0f : 0.0f;
        float f1 = (kb & 4u) ? 1.0f : 0.0f;
        float f2 = (kb & 2u) ? 1.0f : 0.0f;
        float f3 = (kb & 1u) ? 1.0f : 0.0f;
        acc[r][0] = __builtin_fmaf(f0, t0, acc[r][0]);
        acc[r][1] = __builtin_fmaf(f1, t1, acc[r][1]);
        acc[r][2] = __builtin_fmaf(f2, t2, acc[r][2]);
        acc[r][3] = __builtin_fmaf(f3, t3, acc[r][3]);
      }
    }
  }
  float bq0 = bq[c], bq1 = bq[4096 + c], bq2 = bq[2 * 4096 + c], bq3 = bq[3 * 4096 + c];
  float nb0 = nb[c], nb1 = nb[4096 + c], nb2 = nb[2 * 4096 + c], nb3 = nb[3 * 4096 + c];
#pragma unroll
  for (int r = 0; r < 32; ++r) {
    uint32_t Kn = 0;
    float s0 = __fadd_rn(__fadd_rn(acc[r][0], bq0), nb0); if (s0 > 0.5f) Kn |= 8u;
    float s1 = __fadd_rn(__fadd_rn(acc[r][1], bq1), nb1); if (s1 > 0.5f) Kn |= 4u;
    float s2 = __fadd_rn(__fadd_rn(acc[r][2], bq2), nb2); if (s2 > 0.5f) Kn |= 2u;
    float s3 = __fadd_rn(__fadd_rn(acc[r][3], bq3), nb3); if (s3 > 0.5f) Kn |= 1u;
    size_t o = (size_t)(b0 + r) * 4096 + c;
    if (isHH) Kp[o] = (unsigned char)(Kp[o] | (Kn << 4));
    else      Kp[o] = (unsigned char)Kn;
  }
}

// ---------------- elementwise tail ----------------
__device__ __forceinline__ float quant8(float x, float r) {
  float xs = __fdiv_rn(x, r);
  xs = fminf(fmaxf(xs, -0.9921875f), 0.9921875f);
  float q = rintf(__fmul_rn(xs, 128.0f));
  return __fmul_rn(__fdiv_rn(q, 128.0f), r);
}
__device__ __forceinline__ float pactf(float x, float a) { return fminf(fmaxf(x, -a), a); }
__device__ __forceinline__ double sigd(double x) { return 1.0 / (1.0 + exp(-x)); }

__global__ void tail_kernel(const unsigned char* __restrict__ Kp, const float* __restrict__ cx,
                            const float* a1p, const float* a3p, const float* a4p,
                            const float* a5p, const float* a6p, const float* a7p,
                            const float* a8p, const float* a9p, const float* a10p,
                            const float* a11p, float* __restrict__ out) {
  int idx = blockIdx.x * 256 + threadIdx.x;
  if (idx >= 4096 * 1024) return;
  int b = idx >> 10, h = idx & 1023;
  double a1 = (double)a1p[0], a11 = (double)a11p[0];
  const unsigned char* row = Kp + (size_t)b * 4096 + h;
  int pI = row[0], pJ = row[1024], pF = row[2048], pO = row[3072];
  auto gate = [&](int pk) -> double {
    double s1 = (double)(pk & 15) * (1.0 / 15.0);
    double s2 = (double)(pk >> 4) * (1.0 / 15.0);
    return (s1 * (2.0 * a1) - a1) + (s2 * (2.0 * a11) - a11);
  };
  double gi = gate(pI), gj = gate(pJ), gf = gate(pF), go = gate(pO);
  float a3 = a3p[0], a4 = a4p[0], a5 = a5p[0], a6 = a6p[0];
  float a7 = a7p[0], a8 = a8p[0], a9 = a9p[0], a10 = a10p[0], a11f = a11p[0];
  float fg  = quant8(pactf((float)sigd(gf), a3), a3);
  float ig  = quant8(pactf((float)sigd(gi), a4), a4);
  float act = quant8(pactf((float)tanh(gj), a5), a5);
  float og  = quant8(pactf((float)sigd(go), a6), a6);
  float cxv = cx[idx];
  float gc  = quant8(pactf(__fmul_rn(cxv, fg), a7), a7);
  float ai  = quant8(pactf(__fmul_rn(ig, act), a8), a8);
  float nc  = quant8(pactf(__fadd_rn(gc, ai), a9), a9);
  float ac  = quant8(pactf((float)tanh((double)nc), a10), a10);
  float nh  = quant8(pactf(__fmul_rn(ac, og), a11f), a11f);
  out[idx] = nh;
  out[4194304 + idx] = nc;
}

// ============================================================================
extern "C" void kernel_launch(void* const* d_in, const int* in_sizes, int n_in,
                              void* d_out, int out_size, void* d_ws, size_t ws_size,
                              hipStream_t stream) {
  const float* input = (const float*)d_in[0];
  const float* hx    = (const float*)d_in[1];
  const float* cx    = (const float*)d_in[2];
  const float* wih   = (const float*)d_in[3];
  const float* whh   = (const float*)d_in[4];
  const float* bih   = (const float*)d_in[5];
  const float* bhh   = (const float*)d_in[6];
  const float* a1p   = (const float*)d_in[7];
  const float* a3p   = (const float*)d_in[8];
  const float* a4p   = (const float*)d_in[9];
  const float* a5p   = (const float*)d_in[10];
  const float* a6p   = (const float*)d_in[11];
  const float* a7p   = (const float*)d_in[12];
  const float* a8p   = (const float*)d_in[13];
  const float* a9p   = (const float*)d_in[14];
  const float* a10p  = (const float*)d_in[15];
  const float* a11p  = (const float*)d_in[16];

  char* ws = (char*)d_ws;
  unsigned* enc = (unsigned*)ws;                       // [0..3] max encodings
  float* T      = (float*)(ws + 256);                  // reused: ih then hh (max 64 MiB)
  float* bq_ih  = (float*)(ws + 256 + 67108864);
  float* nb_ih  = bq_ih + 16384;
  float* bq_hh  = nb_ih + 16384;
  float* nb_hh  = bq_hh + 16384;
  unsigned char* kv_ih = (unsigned char*)(nb_hh + 16384);  // [256][4096]
  unsigned char* kv_hh = kv_ih + 1048576;                  // [1024][4096]
  unsigned char* Kp    = kv_hh + 4194304;                  // [4096][4096] lo=K1 hi=K2

  hipMemsetAsync(enc, 0, 64, stream);
  rmax_kernel<<<512, 256, 0, stream>>>(wih, 4 * 256 * 4096, enc + 0);
  rmax_kernel<<<512, 256, 0, stream>>>(whh, 4 * 1024 * 4096, enc + 1);
  rmax_kernel<<<64, 256, 0, stream>>>(bih, 16384, enc + 2);
  rmax_kernel<<<64, 256, 0, stream>>>(bhh, 16384, enc + 3);

  kv_kernel<<<4096, 256, 0, stream>>>(input, a1p, a1p, kv_ih, 256);
  kv_kernel<<<16384, 256, 0, stream>>>(hx, a11p, a1p, kv_hh, 1024);

  gen_bias_kernel<<<64, 256, 0, stream>>>(bih, bq_ih, nb_ih, 16384, enc + 2, KBIH.a, KBIH.b);
  gen_bias_kernel<<<64, 256, 0, stream>>>(bhh, bq_hh, nb_hh, 16384, enc + 3, KBHH.a, KBHH.b);

  gen_terms_kernel<<<16384, 256, 0, stream>>>(wih, T, 4 * 256 * 4096, enc + 0, KWIH.a, KWIH.b);
  gemm_bits_kernel<<<dim3(16, 128), 256, 0, stream>>>(T, bq_ih, nb_ih, kv_ih, Kp, 256, 0);

  gen_terms_kernel<<<65536, 256, 0, stream>>>(whh, T, 4 * 1024 * 4096, enc + 1, KWHH.a, KWHH.b);
  gemm_bits_kernel<<<dim3(16, 128), 256, 0, stream>>>(T, bq_hh, nb_hh, kv_hh, Kp, 1024, 1);

  tail_kernel<<<16384, 256, 0, stream>>>(Kp, cx, a1p, a3p, a4p, a5p, a6p, a7p, a8p, a9p,
                                         a10p, a11p, (float*)d_out);
}

// Round 2
// 3593.611 us; speedup vs baseline: 1.9666x; 1.9666x over previous
//
#include <hip/hip_runtime.h>
#include <cstdint>
#include <cstddef>

// ============================================================================
// LSTMCellQ bit-exact reproduction. Round 2: exec-masked row-lane GEMM.
//  - lanes = batch rows; registers = 16 cols x 4 planes of f32 accumulators
//  - bit selection via divergent if -> exec mask (~0 VALU per MAC)
//  - T repacked [k][plane][col]; wave-uniform -> s_load into SGPRs
//  - rounding identical: skipped term == fma(0,t,acc); add == fma(1,t,acc)
// RNG (verified round 1, absmax 0): threefry partitionable, foldlike split,
// bits=x0^x1, CHLO Giles erfinv f32, device logf, rintf round-half-even.
// ============================================================================

struct KPc { uint32_t a, b; };

__host__ __device__ constexpr KPc ctf(uint32_t k0, uint32_t k1v, uint32_t c0, uint32_t c1) {
  uint32_t ks2 = k0 ^ k1v ^ 0x1BD11BDAu;
  uint32_t x0 = c0 + k0;
  uint32_t x1 = c1 + k1v;
  uint32_t r0[4] = {13u, 15u, 26u, 6u};
  uint32_t r1[4] = {17u, 29u, 16u, 24u};
  uint32_t ks[3] = {k0, k1v, ks2};
  for (int g = 0; g < 5; ++g) {
    for (int j = 0; j < 4; ++j) {
      uint32_t rr = (g & 1) ? r1[j] : r0[j];
      x0 += x1;
      x1 = (x1 << rr) | (x1 >> (32u - rr));
      x1 ^= x0;
    }
    x0 += ks[(g + 1) % 3];
    x1 += ks[(g + 2) % 3] + (uint32_t)(g + 1);
  }
  return KPc{x0, x1};
}

constexpr KPc K1K  = ctf(0u, 42u, 0u, 0u);
constexpr KPc K2K  = ctf(0u, 42u, 0u, 1u);
constexpr KPc KWIH = ctf(K1K.a, K1K.b, 0u, 0u);
constexpr KPc KBIH = ctf(K1K.a, K1K.b, 0u, 1u);
constexpr KPc KWHH = ctf(K2K.a, K2K.b, 0u, 0u);
constexpr KPc KBHH = ctf(K2K.a, K2K.b, 0u, 1u);

__device__ __forceinline__ uint32_t tf_bits(uint32_t k0, uint32_t k1v, uint32_t j) {
  KPc r = ctf(k0, k1v, 0u, j);
  return r.a ^ r.b;
}

// ---------------- float max-reduction with order-encoded uint ----------------
__device__ __forceinline__ unsigned encf(float f) {
  unsigned u = __float_as_uint(f);
  return (u & 0x80000000u) ? ~u : (u | 0x80000000u);
}
__device__ __forceinline__ float decf(unsigned e) {
  unsigned u = (e & 0x80000000u) ? (e & 0x7FFFFFFFu) : ~e;
  return __uint_as_float(u);
}

__global__ void rmax_kernel(const float* __restrict__ x, int n, unsigned* __restrict__ out) {
  unsigned best = 0u;
  for (int i = blockIdx.x * blockDim.x + threadIdx.x; i < n; i += gridDim.x * blockDim.x) {
    unsigned e = encf(x[i]);
    best = best > e ? best : e;
  }
  for (int off = 32; off > 0; off >>= 1) {
    unsigned o = __shfl_down(best, off, 64);
    best = best > o ? best : o;
  }
  __shared__ unsigned sm[4];
  int lane = threadIdx.x & 63, wv = threadIdx.x >> 6;
  if (lane == 0) sm[wv] = best;
  __syncthreads();
  if (threadIdx.x == 0) {
    unsigned b = sm[0];
    for (int i = 1; i < 4; ++i) b = b > sm[i] ? b : sm[i];
    atomicMax(out, b);
  }
}

// ---------------- XLA-replicated erfinv / uniform->normal ----------------
__device__ __forceinline__ float xla_log1p(float t) {
  float small = __fmul_rn(__fadd_rn(__fmul_rn(-0.5f, t), 1.0f), t);
  float large = logf(__fadd_rn(t, 1.0f));
  return (fabsf(t) < 1e-4f) ? small : large;
}

__device__ __forceinline__ float xla_erfinv(float x) {
  float w = -xla_log1p(-__fmul_rn(x, x));
  float p;
  if (w < 5.0f) {
    float ww = __fadd_rn(w, -2.5f);
    p = 2.81022636e-08f;
    p = __fadd_rn(3.43273939e-07f, __fmul_rn(p, ww));
    p = __fadd_rn(-3.5233877e-06f, __fmul_rn(p, ww));
    p = __fadd_rn(-4.39150654e-06f, __fmul_rn(p, ww));
    p = __fadd_rn(0.00021858087f, __fmul_rn(p, ww));
    p = __fadd_rn(-0.00125372503f, __fmul_rn(p, ww));
    p = __fadd_rn(-0.00417768164f, __fmul_rn(p, ww));
    p = __fadd_rn(0.246640727f, __fmul_rn(p, ww));
    p = __fadd_rn(1.50140941f, __fmul_rn(p, ww));
  } else {
    float ww = __fadd_rn(sqrtf(w), -3.0f);
    p = -0.000200214257f;
    p = __fadd_rn(0.000100950558f, __fmul_rn(p, ww));
    p = __fadd_rn(0.00134934322f, __fmul_rn(p, ww));
    p = __fadd_rn(-0.00367342844f, __fmul_rn(p, ww));
    p = __fadd_rn(0.00573950773f, __fmul_rn(p, ww));
    p = __fadd_rn(-0.0076224613f, __fmul_rn(p, ww));
    p = __fadd_rn(0.00943887047f, __fmul_rn(p, ww));
    p = __fadd_rn(1.00167406f, __fmul_rn(p, ww));
    p = __fadd_rn(2.83297682f, __fmul_rn(p, ww));
  }
  return __fmul_rn(p, x);
}

__device__ __forceinline__ float normal_from_bits(uint32_t bits) {
  float u01 = __uint_as_float((bits >> 9) | 0x3f800000u) - 1.0f;
  const float lo = -0x1.fffffep-1f;
  float u = fmaxf(lo, __fadd_rn(__fmul_rn(u01, 2.0f), lo));
  return __fmul_rn(0x1.6a09e6p+0f, xla_erfinv(u));
}

__device__ __forceinline__ float quantw(float x) {
  float xs = fminf(fmaxf(x, -0.9921875f), 0.9921875f);
  return __fmul_rn(rintf(__fmul_rn(xs, 128.0f)), 0.0078125f);
}

// ---------------- noisy term materialization, repacked to [k][plane][col] ---
__global__ void gen_terms_kernel(const float* __restrict__ W, float* __restrict__ T2, int n,
                                 int K, const unsigned* __restrict__ encp,
                                 uint32_t k0, uint32_t k1v) {
  int j = blockIdx.x * 256 + threadIdx.x;
  if (j >= n) return;
  float wmax = decf(*encp);
  float nrm = normal_from_bits(tf_bits(k0, k1v, (uint32_t)j));
  float nw = __fmul_rn(__fmul_rn(nrm, wmax), 0.1f);
  float val = __fadd_rn(quantw(W[j]), nw);
  // source j = ((m*K + k) << 12) + c  ->  dst = ((k*4 + m) << 12) + c
  int m = j >> 12; int c = j & 4095;
  int k = m % K;  m = m / K;
  T2[(((size_t)k * 4 + m) << 12) + c] = val;
}

__global__ void gen_bias_kernel(const float* __restrict__ bsrc, float* __restrict__ bq,
                                float* __restrict__ nb, int n,
                                const unsigned* __restrict__ encp, uint32_t k0, uint32_t k1v) {
  int j = blockIdx.x * 256 + threadIdx.x;
  if (j >= n) return;
  float bmax = decf(*encp);
  float nrm = normal_from_bits(tf_bits(k0, k1v, (uint32_t)j));
  bq[j] = quantw(bsrc[j]);
  nb[j] = __fmul_rn(__fmul_rn(nrm, bmax), 0.1f);
}

// ---------------- bitplane nibble precompute ([k][row] layout) ----------------
__global__ void kv_kernel(const float* __restrict__ x, const float* __restrict__ ap,
                          const float* __restrict__ offp, unsigned char* __restrict__ kvT,
                          int Kdim) {
  int j = blockIdx.x * 256 + threadIdx.x;
  int n = 4096 * Kdim;
  if (j >= n) return;
  int b = j / Kdim, i = j - b * Kdim;
  float a = ap[0], off = offp[0];
  float v = fmaxf(-a, fminf(x[j], a));
  float t = __fdiv_rn(__fadd_rn(v, off), __fmul_rn(a, 2.0f));
  int k = (int)rintf(__fmul_rn(15.0f, t));
  kvT[(size_t)i * 4096 + b] = (unsigned char)(k & 15);
}

// ---------------- exec-masked binary GEMM ----------------
// 1 wave per block: lanes = 64 rows, regs = 16 cols x 4 planes.
// t values are wave-uniform (blockIdx-derived address) -> SGPRs -> v_add v,s,v.
// Exactness: conditional add == reference's fma(bit, t, acc) chain, k-ascending.
__global__ __launch_bounds__(64) void gemm_bits_kernel(
    const float* __restrict__ T2, const float* __restrict__ bq, const float* __restrict__ nb,
    const unsigned char* __restrict__ kvT, unsigned char* __restrict__ Kp,
    int K, int isHH) {
  const int lane = threadIdx.x;
  const int c0 = blockIdx.x * 16;
  const int row = blockIdx.y * 64 + lane;

  float acc0[16], acc1[16], acc2[16], acc3[16];
#pragma unroll
  for (int j = 0; j < 16; ++j) { acc0[j] = 0.f; acc1[j] = 0.f; acc2[j] = 0.f; acc3[j] = 0.f; }

  const unsigned char* kvp = kvT + row;
  unsigned nib = kvp[0];
  for (int k = 0; k < K; ++k) {
    unsigned nibn = (k + 1 < K) ? kvp[(size_t)(k + 1) << 12] : 0u;  // prefetch
    const float* t = T2 + ((size_t)k << 14) + c0;                   // uniform addr
    float tv0[16], tv1[16], tv2[16], tv3[16];
#pragma unroll
    for (int j = 0; j < 16; ++j) {
      tv0[j] = t[j];
      tv1[j] = t[4096 + j];
      tv2[j] = t[8192 + j];
      tv3[j] = t[12288 + j];
    }
    if (nib & 8u) {
#pragma unroll
      for (int j = 0; j < 16; ++j) acc0[j] = __fadd_rn(acc0[j], tv0[j]);
    }
    if (nib & 4u) {
#pragma unroll
      for (int j = 0; j < 16; ++j) acc1[j] = __fadd_rn(acc1[j], tv1[j]);
    }
    if (nib & 2u) {
#pragma unroll
      for (int j = 0; j < 16; ++j) acc2[j] = __fadd_rn(acc2[j], tv2[j]);
    }
    if (nib & 1u) {
#pragma unroll
      for (int j = 0; j < 16; ++j) acc3[j] = __fadd_rn(acc3[j], tv3[j]);
    }
    nib = nibn;
  }

  // epilogue: s = (acc + bq) + nb; bit = s > 0.5; pack 16 bytes -> one uint4
  unsigned res[4] = {0u, 0u, 0u, 0u};
#pragma unroll
  for (int j = 0; j < 16; ++j) {
    int col = c0 + j;
    unsigned byte = 0u;
    float s0 = __fadd_rn(__fadd_rn(acc0[j], bq[col]),           nb[col]);
    float s1 = __fadd_rn(__fadd_rn(acc1[j], bq[4096 + col]),    nb[4096 + col]);
    float s2 = __fadd_rn(__fadd_rn(acc2[j], bq[8192 + col]),    nb[8192 + col]);
    float s3 = __fadd_rn(__fadd_rn(acc3[j], bq[12288 + col]),   nb[12288 + col]);
    if (s0 > 0.5f) byte |= 8u;
    if (s1 > 0.5f) byte |= 4u;
    if (s2 > 0.5f) byte |= 2u;
    if (s3 > 0.5f) byte |= 1u;
    if (isHH) byte <<= 4;
    res[j >> 2] |= byte << ((j & 3) * 8);
  }
  uint4* dst = (uint4*)(Kp + (size_t)row * 4096 + c0);
  if (isHH) {
    uint4 o = *dst;
    o.x |= res[0]; o.y |= res[1]; o.z |= res[2]; o.w |= res[3];
    *dst = o;
  } else {
    uint4 o; o.x = res[0]; o.y = res[1]; o.z = res[2]; o.w = res[3];
    *dst = o;
  }
}

// ---------------- elementwise tail ----------------
__device__ __forceinline__ float quant8(float x, float r) {
  float xs = __fdiv_rn(x, r);
  xs = fminf(fmaxf(xs, -0.9921875f), 0.9921875f);
  float q = rintf(__fmul_rn(xs, 128.0f));
  return __fmul_rn(__fdiv_rn(q, 128.0f), r);
}
__device__ __forceinline__ float pactf(float x, float a) { return fminf(fmaxf(x, -a), a); }
__device__ __forceinline__ double sigd(double x) { return 1.0 / (1.0 + exp(-x)); }

__global__ void tail_kernel(const unsigned char* __restrict__ Kp, const float* __restrict__ cx,
                            const float* a1p, const float* a3p, const float* a4p,
                            const float* a5p, const float* a6p, const float* a7p,
                            const float* a8p, const float* a9p, const float* a10p,
                            const float* a11p, float* __restrict__ out) {
  int idx = blockIdx.x * 256 + threadIdx.x;
  if (idx >= 4096 * 1024) return;
  int b = idx >> 10, h = idx & 1023;
  double a1 = (double)a1p[0], a11 = (double)a11p[0];
  const unsigned char* row = Kp + (size_t)b * 4096 + h;
  int pI = row[0], pJ = row[1024], pF = row[2048], pO = row[3072];
  auto gate = [&](int pk) -> double {
    double s1 = (double)(pk & 15) * (1.0 / 15.0);
    double s2 = (double)(pk >> 4) * (1.0 / 15.0);
    return (s1 * (2.0 * a1) - a1) + (s2 * (2.0 * a11) - a11);
  };
  double gi = gate(pI), gj = gate(pJ), gf = gate(pF), go = gate(pO);
  float a3 = a3p[0], a4 = a4p[0], a5 = a5p[0], a6 = a6p[0];
  float a7 = a7p[0], a8 = a8p[0], a9 = a9p[0], a10 = a10p[0], a11f = a11p[0];
  float fg  = quant8(pactf((float)sigd(gf), a3), a3);
  float ig  = quant8(pactf((float)sigd(gi), a4), a4);
  float act = quant8(pactf((float)tanh(gj), a5), a5);
  float og  = quant8(pactf((float)sigd(go), a6), a6);
  float cxv = cx[idx];
  float gc  = quant8(pactf(__fmul_rn(cxv, fg), a7), a7);
  float ai  = quant8(pactf(__fmul_rn(ig, act), a8), a8);
  float nc  = quant8(pactf(__fadd_rn(gc, ai), a9), a9);
  float ac  = quant8(pactf((float)tanh((double)nc), a10), a10);
  float nh  = quant8(pactf(__fmul_rn(ac, og), a11f), a11f);
  out[idx] = nh;
  out[4194304 + idx] = nc;
}

// ============================================================================
extern "C" void kernel_launch(void* const* d_in, const int* in_sizes, int n_in,
                              void* d_out, int out_size, void* d_ws, size_t ws_size,
                              hipStream_t stream) {
  const float* input = (const float*)d_in[0];
  const float* hx    = (const float*)d_in[1];
  const float* cx    = (const float*)d_in[2];
  const float* wih   = (const float*)d_in[3];
  const float* whh   = (const float*)d_in[4];
  const float* bih   = (const float*)d_in[5];
  const float* bhh   = (const float*)d_in[6];
  const float* a1p   = (const float*)d_in[7];
  const float* a3p   = (const float*)d_in[8];
  const float* a4p   = (const float*)d_in[9];
  const float* a5p   = (const float*)d_in[10];
  const float* a6p   = (const float*)d_in[11];
  const float* a7p   = (const float*)d_in[12];
  const float* a8p   = (const float*)d_in[13];
  const float* a9p   = (const float*)d_in[14];
  const float* a10p  = (const float*)d_in[15];
  const float* a11p  = (const float*)d_in[16];

  char* ws = (char*)d_ws;
  unsigned* enc = (unsigned*)ws;
  float* T2     = (float*)(ws + 256);                  // [k][4 planes][4096], max 64 MiB
  float* bq_ih  = (float*)(ws + 256 + 67108864);
  float* nb_ih  = bq_ih + 16384;
  float* bq_hh  = nb_ih + 16384;
  float* nb_hh  = bq_hh + 16384;
  unsigned char* kv_ih = (unsigned char*)(nb_hh + 16384);  // [256][4096]
  unsigned char* kv_hh = kv_ih + 1048576;                  // [1024][4096]
  unsigned char* Kp    = kv_hh + 4194304;                  // [4096][4096] lo=K1 hi=K2

  hipMemsetAsync(enc, 0, 64, stream);
  rmax_kernel<<<512, 256, 0, stream>>>(wih, 4 * 256 * 4096, enc + 0);
  rmax_kernel<<<512, 256, 0, stream>>>(whh, 4 * 1024 * 4096, enc + 1);
  rmax_kernel<<<64, 256, 0, stream>>>(bih, 16384, enc + 2);
  rmax_kernel<<<64, 256, 0, stream>>>(bhh, 16384, enc + 3);

  kv_kernel<<<4096, 256, 0, stream>>>(input, a1p, a1p, kv_ih, 256);
  kv_kernel<<<16384, 256, 0, stream>>>(hx, a11p, a1p, kv_hh, 1024);

  gen_bias_kernel<<<64, 256, 0, stream>>>(bih, bq_ih, nb_ih, 16384, enc + 2, KBIH.a, KBIH.b);
  gen_bias_kernel<<<64, 256, 0, stream>>>(bhh, bq_hh, nb_hh, 16384, enc + 3, KBHH.a, KBHH.b);

  gen_terms_kernel<<<16384, 256, 0, stream>>>(wih, T2, 4 * 256 * 4096, 256, enc + 0, KWIH.a, KWIH.b);
  gemm_bits_kernel<<<dim3(256, 64), 64, 0, stream>>>(T2, bq_ih, nb_ih, kv_ih, Kp, 256, 0);

  gen_terms_kernel<<<65536, 256, 0, stream>>>(whh, T2, 4 * 1024 * 4096, 1024, enc + 1, KWHH.a, KWHH.b);
  gemm_bits_kernel<<<dim3(256, 64), 64, 0, stream>>>(T2, bq_hh, nb_hh, kv_hh, Kp, 1024, 1);

  tail_kernel<<<16384, 256, 0, stream>>>(Kp, cx, a1p, a3p, a4p, a5p, a6p, a7p, a8p, a9p,
                                         a10p, a11p, (float*)d_out);
}